// Round 1
// baseline (675.685 us; speedup 1.0000x reference)
//
#include <hip/hip_runtime.h>
#include <stdint.h>

typedef __attribute__((ext_vector_type(8))) short short8;
typedef __attribute__((ext_vector_type(4))) float f32x4;

#define DEVI static __device__ __forceinline__

DEVI unsigned short f2bf(float f) {
  unsigned int u = __builtin_bit_cast(unsigned int, f);
  u += 0x7fffu + ((u >> 16) & 1u);
  return (unsigned short)(u >> 16);
}

DEVI void glds16(const void* g, void* lds_uniform) {
  typedef const __attribute__((address_space(1))) unsigned int* gp_t;
  typedef __attribute__((address_space(3))) unsigned int* lp_t;
  __builtin_amdgcn_global_load_lds((gp_t)(uintptr_t)g, (lp_t)(uintptr_t)lds_uniform, 16, 0, 0);
}

// ---------------- conversions ----------------

__global__ __launch_bounds__(256) void cvt_x_kernel(const float* __restrict__ in,
                                                    unsigned short* __restrict__ out, int n4) {
  typedef __attribute__((ext_vector_type(4))) float f4;
  typedef __attribute__((ext_vector_type(4))) unsigned short u4;
  const f4* in4 = (const f4*)in;
  u4* out4 = (u4*)out;
  for (int i = blockIdx.x * blockDim.x + threadIdx.x; i < n4; i += gridDim.x * blockDim.x) {
    f4 v = in4[i];
    u4 o;
    o[0] = f2bf(v[0]); o[1] = f2bf(v[1]); o[2] = f2bf(v[2]); o[3] = f2bf(v[3]);
    out4[i] = o;
  }
}

// transpose-convert: in fp32 [B][R=1024][C], out bf16 [B][C][R]; C,R pow2, R=1024
__global__ __launch_bounds__(256) void cvt_w_kernel(const float* __restrict__ in,
                                                    unsigned short* __restrict__ out,
                                                    int total, int log2C) {
  int i = blockIdx.x * blockDim.x + threadIdx.x;
  if (i >= total) return;
  int r = i & 1023;
  int rest = i >> 10;
  int c = rest & ((1 << log2C) - 1);
  int b = rest >> log2C;
  out[i] = f2bf(in[((((size_t)b << 10) | (size_t)r) << log2C) | (size_t)c]);
}

// ---------------- GEMM: C[M x N] = A[M x K] * Bt[N x K]^T, K=1024 ----------------
// MODE 0: out bf16 scattered to qkv layout [(b*16+h)*1024+t]*64+d, z selects q/k/v
// MODE 1: out fp32 row-major [M][1024] + bias
template <int MODE>
__global__ __launch_bounds__(256)
void gemm128(const unsigned short* __restrict__ A,
             const unsigned short* __restrict__ Bt,
             unsigned short* __restrict__ OutB,
             float* __restrict__ OutF,
             const float* __restrict__ bias) {
  __shared__ unsigned short As[128 * 64];  // [row][64], chunk-swizzled
  __shared__ unsigned short Bs[128 * 64];
  const int tid = threadIdx.x;
  const int w = tid >> 6, lane = tid & 63;
  const int l15 = lane & 15, l4 = lane >> 4;
  const int bm = blockIdx.y << 7, bn = blockIdx.x << 7;
  const unsigned short* Bz = Bt + (size_t)blockIdx.z * (1024 * 1024);

  f32x4 acc[4][4];
#pragma unroll
  for (int i = 0; i < 4; ++i)
#pragma unroll
    for (int j = 0; j < 4; ++j) acc[i][j] = f32x4{0.f, 0.f, 0.f, 0.f};

  const int wr = w >> 1, wc = w & 1;

  // staging: thread's chunk C = (j*4+w)*64 + lane; row=C>>3, slot cc=C&7 holds k-chunk cc^(row&7)
  int Crow[4], Kel[4];
#pragma unroll
  for (int j = 0; j < 4; ++j) {
    int C = (((j << 2) + w) << 6) + lane;
    int row = C >> 3, cc = C & 7;
    Crow[j] = row;
    Kel[j] = ((cc ^ (row & 7)) << 3);
  }

  for (int kt = 0; kt < 16; ++kt) {
    int k0 = kt << 6;
#pragma unroll
    for (int j = 0; j < 4; ++j) {
      const unsigned short* g = A + (size_t)(bm + Crow[j]) * 1024 + k0 + Kel[j];
      glds16(g, &As[(size_t)(((j << 2) + w) << 6) * 8]);
    }
#pragma unroll
    for (int j = 0; j < 4; ++j) {
      const unsigned short* g = Bz + (size_t)(bn + Crow[j]) * 1024 + k0 + Kel[j];
      glds16(g, &Bs[(size_t)(((j << 2) + w) << 6) * 8]);
    }
    __syncthreads();
#pragma unroll
    for (int ks = 0; ks < 2; ++ks) {
      short8 af[4], bfr[4];
#pragma unroll
      for (int mi = 0; mi < 4; ++mi) {
        int row = (wr << 6) + (mi << 4) + l15;
        int ch = ((ks << 2) + l4) ^ (row & 7);
        af[mi] = *(const short8*)&As[(row << 6) + (ch << 3)];
      }
#pragma unroll
      for (int ni = 0; ni < 4; ++ni) {
        int row = (wc << 6) + (ni << 4) + l15;
        int ch = ((ks << 2) + l4) ^ (row & 7);
        bfr[ni] = *(const short8*)&Bs[(row << 6) + (ch << 3)];
      }
#pragma unroll
      for (int mi = 0; mi < 4; ++mi)
#pragma unroll
        for (int ni = 0; ni < 4; ++ni)
          acc[mi][ni] = __builtin_amdgcn_mfma_f32_16x16x32_bf16(af[mi], bfr[ni], acc[mi][ni], 0, 0, 0);
    }
    __syncthreads();
  }

  if (MODE == 0) {
    unsigned short* Oz = OutB + (size_t)blockIdx.z * 16777216;
#pragma unroll
    for (int mi = 0; mi < 4; ++mi) {
#pragma unroll
      for (int r = 0; r < 4; ++r) {
        int m = bm + (wr << 6) + (mi << 4) + (l4 << 2) + r;
        int b = m >> 10, t = m & 1023;
#pragma unroll
        for (int ni = 0; ni < 4; ++ni) {
          int n = bn + (wc << 6) + (ni << 4) + l15;
          int h = n >> 6, d = n & 63;
          Oz[((size_t)(b * 16 + h) * 1024 + t) * 64 + d] = f2bf(acc[mi][ni][r]);
        }
      }
    }
  } else {
#pragma unroll
    for (int mi = 0; mi < 4; ++mi) {
#pragma unroll
      for (int r = 0; r < 4; ++r) {
        int m = bm + (wr << 6) + (mi << 4) + (l4 << 2) + r;
#pragma unroll
        for (int ni = 0; ni < 4; ++ni) {
          int n = bn + (wc << 6) + (ni << 4) + l15;
          OutF[(size_t)m * 1024 + n] = acc[mi][ni][r] + bias[n];
        }
      }
    }
  }
}

// ---------------- causal flash attention ----------------
// grid (T/64, B*H), 256 threads = 4 waves, wave w owns Q rows [q0+16w, q0+16w+16)
__global__ __launch_bounds__(256)
void attn64(const unsigned short* __restrict__ Qb,
            const unsigned short* __restrict__ Kb,
            const unsigned short* __restrict__ Vb,
            unsigned short* __restrict__ Ob) {
  __shared__ unsigned short Ps[4 * 16 * 64];  // per-wave P tile, chunk-swizzled
  __shared__ unsigned short Vt[64 * 64];      // V^T [d][kv], chunk-swizzled
  const int tid = threadIdx.x, w = tid >> 6, lane = tid & 63;
  const int l15 = lane & 15, l4 = lane >> 4;
  const int qidx = blockIdx.x, bh = blockIdx.y;
  const int q0 = qidx << 6;
  const unsigned short* Q = Qb + ((size_t)bh << 16);
  const unsigned short* K = Kb + ((size_t)bh << 16);
  const unsigned short* V = Vb + ((size_t)bh << 16);

  short8 aq[2];
  {
    int t = q0 + (w << 4) + l15;
    aq[0] = *(const short8*)&Q[t * 64 + (l4 << 3)];
    aq[1] = *(const short8*)&Q[t * 64 + 32 + (l4 << 3)];
  }

  f32x4 o[4];
  float mreg[4], lreg[4];
#pragma unroll
  for (int n = 0; n < 4; ++n) o[n] = f32x4{0.f, 0.f, 0.f, 0.f};
#pragma unroll
  for (int r = 0; r < 4; ++r) { mreg[r] = -__builtin_inff(); lreg[r] = 0.f; }

  const float SC = 0.125f * 1.44269504088896340736f;  // 1/sqrt(64) * log2(e)
  const int nt = qidx + 1;
  const int v_kv = tid & 63, v_dg = tid >> 6;

  for (int it = 0; it < nt; ++it) {
    int kv0 = it << 6;
    __syncthreads();  // protect Ps/Vt from previous iteration's readers

    // stage V^T (cooperative): element (kv,d) -> Vt[d*64 + ((kv>>3)^(d&7))*8 + (kv&7)]
    {
      short8 v0 = *(const short8*)&V[(size_t)(kv0 + v_kv) * 64 + (v_dg << 4)];
      short8 v1 = *(const short8*)&V[(size_t)(kv0 + v_kv) * 64 + (v_dg << 4) + 8];
      int ck = v_kv >> 3, ke = v_kv & 7;
#pragma unroll
      for (int j = 0; j < 8; ++j) {
        int d = (v_dg << 4) + j;
        Vt[(d << 6) + ((ck ^ (d & 7)) << 3) + ke] = (unsigned short)v0[j];
        int d2 = d + 8;
        Vt[(d2 << 6) + ((ck ^ (d2 & 7)) << 3) + ke] = (unsigned short)v1[j];
      }
    }

    // S = Q K^T (K fragments direct from global)
    f32x4 s[4];
#pragma unroll
    for (int n = 0; n < 4; ++n) s[n] = f32x4{0.f, 0.f, 0.f, 0.f};
#pragma unroll
    for (int n = 0; n < 4; ++n) {
      int kr = kv0 + (n << 4) + l15;
      short8 bk0 = *(const short8*)&K[(size_t)kr * 64 + (l4 << 3)];
      short8 bk1 = *(const short8*)&K[(size_t)kr * 64 + 32 + (l4 << 3)];
      s[n] = __builtin_amdgcn_mfma_f32_16x16x32_bf16(aq[0], bk0, s[n], 0, 0, 0);
      s[n] = __builtin_amdgcn_mfma_f32_16x16x32_bf16(aq[1], bk1, s[n], 0, 0, 0);
    }

    // online softmax (exp2 domain); C layout: row=(l4*4+r), col=(n*16+l15)
    const bool needmask = (kv0 + 63) > (q0 + (w << 4));
    float p[4][4], mx[4];
#pragma unroll
    for (int r = 0; r < 4; ++r) mx[r] = -__builtin_inff();
#pragma unroll
    for (int n = 0; n < 4; ++n) {
#pragma unroll
      for (int r = 0; r < 4; ++r) {
        float v = s[n][r] * SC;
        if (needmask) {
          int row = q0 + (w << 4) + (l4 << 2) + r;
          int col = kv0 + (n << 4) + l15;
          if (col > row) v = -__builtin_inff();
        }
        p[n][r] = v;
        mx[r] = fmaxf(mx[r], v);
      }
    }
#pragma unroll
    for (int r = 0; r < 4; ++r) {
      mx[r] = fmaxf(mx[r], __shfl_xor(mx[r], 1));
      mx[r] = fmaxf(mx[r], __shfl_xor(mx[r], 2));
      mx[r] = fmaxf(mx[r], __shfl_xor(mx[r], 4));
      mx[r] = fmaxf(mx[r], __shfl_xor(mx[r], 8));
    }
    float alpha[4], rs[4];
#pragma unroll
    for (int r = 0; r < 4; ++r) {
      float mnew = fmaxf(mreg[r], mx[r]);
      alpha[r] = exp2f(mreg[r] - mnew);
      mreg[r] = mnew;
      rs[r] = 0.f;
    }
#pragma unroll
    for (int n = 0; n < 4; ++n)
#pragma unroll
      for (int r = 0; r < 4; ++r) {
        float pv = exp2f(p[n][r] - mreg[r]);
        p[n][r] = pv;
        rs[r] += pv;
      }
#pragma unroll
    for (int r = 0; r < 4; ++r) {
      rs[r] += __shfl_xor(rs[r], 1);
      rs[r] += __shfl_xor(rs[r], 2);
      rs[r] += __shfl_xor(rs[r], 4);
      rs[r] += __shfl_xor(rs[r], 8);
      lreg[r] = lreg[r] * alpha[r] + rs[r];
#pragma unroll
      for (int n = 0; n < 4; ++n) o[n][r] *= alpha[r];
    }

    // write P (bf16) to per-wave swizzled LDS region
#pragma unroll
    for (int n = 0; n < 4; ++n)
#pragma unroll
      for (int r = 0; r < 4; ++r) {
        int row = (l4 << 2) + r;
        int col = (n << 4) + l15;
        Ps[(w << 10) + (row << 6) + (((col >> 3) ^ (row & 7)) << 3) + (col & 7)] = f2bf(p[n][r]);
      }
    __syncthreads();

    // O += P V
    short8 pa[2];
    pa[0] = *(const short8*)&Ps[(w << 10) + (l15 << 6) + ((l4 ^ (l15 & 7)) << 3)];
    pa[1] = *(const short8*)&Ps[(w << 10) + (l15 << 6) + (((4 + l4) ^ (l15 & 7)) << 3)];
#pragma unroll
    for (int nf = 0; nf < 4; ++nf) {
      int d = (nf << 4) + l15;
      short8 vb0 = *(const short8*)&Vt[(d << 6) + ((l4 ^ (d & 7)) << 3)];
      short8 vb1 = *(const short8*)&Vt[(d << 6) + (((4 + l4) ^ (d & 7)) << 3)];
      o[nf] = __builtin_amdgcn_mfma_f32_16x16x32_bf16(pa[0], vb0, o[nf], 0, 0, 0);
      o[nf] = __builtin_amdgcn_mfma_f32_16x16x32_bf16(pa[1], vb1, o[nf], 0, 0, 0);
    }
  }

  // normalize + write O as [b][t][h*64+d] bf16
  int b = bh >> 4, h = bh & 15;
#pragma unroll
  for (int r = 0; r < 4; ++r) {
    float inv = 1.0f / lreg[r];
    int t = q0 + (w << 4) + (l4 << 2) + r;
    size_t base = (((size_t)b * 1024 + t) * 1024) + (h << 6);
#pragma unroll
    for (int nf = 0; nf < 4; ++nf) {
      Ob[base + (nf << 4) + l15] = f2bf(o[nf][r] * inv);
    }
  }
}

// ---------------- launch ----------------

extern "C" void kernel_launch(void* const* d_in, const int* in_sizes, int n_in,
                              void* d_out, int out_size, void* d_ws, size_t ws_size,
                              hipStream_t stream) {
  const float* x  = (const float*)d_in[0];
  const float* Wq = (const float*)d_in[1];
  const float* Wk = (const float*)d_in[2];
  const float* Wv = (const float*)d_in[3];
  const float* Wo = (const float*)d_in[4];
  const float* bo = (const float*)d_in[5];
  float* out = (float*)d_out;

  unsigned char* ws = (unsigned char*)d_ws;
  unsigned short* xb  = (unsigned short*)(ws);                          // 33,554,432 B (aliased by O later)
  unsigned short* wT  = (unsigned short*)(ws + 33554432);               // 3 x 2 MB (WqT,WkT,WvT)
  unsigned short* woT = (unsigned short*)(ws + 33554432 + 6291456);     // 2 MB
  unsigned short* qkv = (unsigned short*)(ws + 41943040);               // 3 x 33,554,432 B
  unsigned short* Ob  = xb;  // x bf16 is dead after projections

  cvt_x_kernel<<<2048, 256, 0, stream>>>(x, xb, 4194304);
  cvt_w_kernel<<<4096, 256, 0, stream>>>(Wq, wT,              1 << 20, 6);
  cvt_w_kernel<<<4096, 256, 0, stream>>>(Wk, wT + (1 << 20),  1 << 20, 6);
  cvt_w_kernel<<<4096, 256, 0, stream>>>(Wv, wT + (2 << 20),  1 << 20, 6);
  cvt_w_kernel<<<4096, 256, 0, stream>>>(Wo, woT,             1 << 20, 10);

  gemm128<0><<<dim3(8, 128, 3), 256, 0, stream>>>(xb, wT, qkv, nullptr, nullptr);
  attn64<<<dim3(16, 256), 256, 0, stream>>>(qkv, qkv + 16777216, qkv + 33554432, Ob);
  gemm128<1><<<dim3(8, 128, 1), 256, 0, stream>>>(Ob, woT, nullptr, out, bo);
}

// Round 2
// 452.771 us; speedup vs baseline: 1.4923x; 1.4923x over previous
//
#include <hip/hip_runtime.h>
#include <stdint.h>

typedef __attribute__((ext_vector_type(8))) short short8;
typedef __attribute__((ext_vector_type(4))) float f32x4;
typedef __attribute__((ext_vector_type(4))) unsigned short u16x4;

#define DEVI static __device__ __forceinline__

DEVI unsigned short f2bf(float f) {
  unsigned int u = __builtin_bit_cast(unsigned int, f);
  u += 0x7fffu + ((u >> 16) & 1u);
  return (unsigned short)(u >> 16);
}

DEVI void glds16(const void* g, void* lds_uniform) {
  typedef const __attribute__((address_space(1))) unsigned int* gp_t;
  typedef __attribute__((address_space(3))) unsigned int* lp_t;
  __builtin_amdgcn_global_load_lds((gp_t)(uintptr_t)g, (lp_t)(uintptr_t)lds_uniform, 16, 0, 0);
}

// ---------------- conversions ----------------

__global__ __launch_bounds__(256) void cvt_x_kernel(const float* __restrict__ in,
                                                    unsigned short* __restrict__ out, int n4) {
  typedef __attribute__((ext_vector_type(4))) float f4;
  typedef __attribute__((ext_vector_type(4))) unsigned short u4;
  const f4* in4 = (const f4*)in;
  u4* out4 = (u4*)out;
  for (int i = blockIdx.x * blockDim.x + threadIdx.x; i < n4; i += gridDim.x * blockDim.x) {
    f4 v = in4[i];
    u4 o;
    o[0] = f2bf(v[0]); o[1] = f2bf(v[1]); o[2] = f2bf(v[2]); o[3] = f2bf(v[3]);
    out4[i] = o;
  }
}

// transpose-convert: in fp32 [B][R=1024][C], out bf16 [B][C][R]; C,R pow2, R=1024
__global__ __launch_bounds__(256) void cvt_w_kernel(const float* __restrict__ in,
                                                    unsigned short* __restrict__ out,
                                                    int total, int log2C) {
  int i = blockIdx.x * blockDim.x + threadIdx.x;
  if (i >= total) return;
  int r = i & 1023;
  int rest = i >> 10;
  int c = rest & ((1 << log2C) - 1);
  int b = rest >> log2C;
  out[i] = f2bf(in[((((size_t)b << 10) | (size_t)r) << log2C) | (size_t)c]);
}

// ---------------- GEMM: C[M x N] = A[M x K] * Bt[N x K]^T, K=1024 ----------------
// MODE 0: z=0,1 -> bf16 scattered to [bh][t][d]; z=2 -> V^T bf16 [bh][d][t] (packed x4)
// MODE 1: out fp32 row-major [M][1024] + bias
template <int MODE>
__global__ __launch_bounds__(256)
void gemm128(const unsigned short* __restrict__ A,
             const unsigned short* __restrict__ Bt,
             unsigned short* __restrict__ OutB,
             float* __restrict__ OutF,
             const float* __restrict__ bias) {
  __shared__ unsigned short As[128 * 64];  // [row][64], chunk-swizzled
  __shared__ unsigned short Bs[128 * 64];
  const int tid = threadIdx.x;
  const int w = tid >> 6, lane = tid & 63;
  const int l15 = lane & 15, l4 = lane >> 4;
  const int bm = blockIdx.y << 7, bn = blockIdx.x << 7;
  const unsigned short* Bz = Bt + (size_t)blockIdx.z * (1024 * 1024);

  f32x4 acc[4][4];
#pragma unroll
  for (int i = 0; i < 4; ++i)
#pragma unroll
    for (int j = 0; j < 4; ++j) acc[i][j] = f32x4{0.f, 0.f, 0.f, 0.f};

  const int wr = w >> 1, wc = w & 1;

  int Crow[4], Kel[4];
#pragma unroll
  for (int j = 0; j < 4; ++j) {
    int C = (((j << 2) + w) << 6) + lane;
    int row = C >> 3, cc = C & 7;
    Crow[j] = row;
    Kel[j] = ((cc ^ (row & 7)) << 3);
  }

  for (int kt = 0; kt < 16; ++kt) {
    int k0 = kt << 6;
#pragma unroll
    for (int j = 0; j < 4; ++j) {
      const unsigned short* g = A + (size_t)(bm + Crow[j]) * 1024 + k0 + Kel[j];
      glds16(g, &As[(size_t)(((j << 2) + w) << 6) * 8]);
    }
#pragma unroll
    for (int j = 0; j < 4; ++j) {
      const unsigned short* g = Bz + (size_t)(bn + Crow[j]) * 1024 + k0 + Kel[j];
      glds16(g, &Bs[(size_t)(((j << 2) + w) << 6) * 8]);
    }
    __syncthreads();
#pragma unroll
    for (int ks = 0; ks < 2; ++ks) {
      short8 af[4], bfr[4];
#pragma unroll
      for (int mi = 0; mi < 4; ++mi) {
        int row = (wr << 6) + (mi << 4) + l15;
        int ch = ((ks << 2) + l4) ^ (row & 7);
        af[mi] = *(const short8*)&As[(row << 6) + (ch << 3)];
      }
#pragma unroll
      for (int ni = 0; ni < 4; ++ni) {
        int row = (wc << 6) + (ni << 4) + l15;
        int ch = ((ks << 2) + l4) ^ (row & 7);
        bfr[ni] = *(const short8*)&Bs[(row << 6) + (ch << 3)];
      }
#pragma unroll
      for (int mi = 0; mi < 4; ++mi)
#pragma unroll
        for (int ni = 0; ni < 4; ++ni)
          acc[mi][ni] = __builtin_amdgcn_mfma_f32_16x16x32_bf16(af[mi], bfr[ni], acc[mi][ni], 0, 0, 0);
    }
    __syncthreads();
  }

  if (MODE == 0) {
    if (blockIdx.z < 2) {
      unsigned short* Oz = OutB + (size_t)blockIdx.z * 16777216;
#pragma unroll
      for (int mi = 0; mi < 4; ++mi) {
#pragma unroll
        for (int r = 0; r < 4; ++r) {
          int m = bm + (wr << 6) + (mi << 4) + (l4 << 2) + r;
          int b = m >> 10, t = m & 1023;
#pragma unroll
          for (int ni = 0; ni < 4; ++ni) {
            int n = bn + (wc << 6) + (ni << 4) + l15;
            int h = n >> 6, d = n & 63;
            Oz[((size_t)(b * 16 + h) * 1024 + t) * 64 + d] = f2bf(acc[mi][ni][r]);
          }
        }
      }
    } else {
      // V^T: [bh][d][t], pack 4 consecutive t per lane
      unsigned short* Oz = OutB + (size_t)2 * 16777216;
#pragma unroll
      for (int mi = 0; mi < 4; ++mi) {
        int tb = bm + (wr << 6) + (mi << 4) + (l4 << 2);
        int bb = tb >> 10, tt = tb & 1023;
#pragma unroll
        for (int ni = 0; ni < 4; ++ni) {
          int n = bn + (wc << 6) + (ni << 4) + l15;
          int hh = n >> 6, dd = n & 63;
          u16x4 pk;
#pragma unroll
          for (int r = 0; r < 4; ++r) pk[r] = f2bf(acc[mi][ni][r]);
          *(u16x4*)&Oz[(((size_t)((bb << 4) + hh) << 6) + (size_t)dd) * 1024 + tt] = pk;
        }
      }
    }
  } else {
#pragma unroll
    for (int mi = 0; mi < 4; ++mi) {
#pragma unroll
      for (int r = 0; r < 4; ++r) {
        int m = bm + (wr << 6) + (mi << 4) + (l4 << 2) + r;
#pragma unroll
        for (int ni = 0; ni < 4; ++ni) {
          int n = bn + (wc << 6) + (ni << 4) + l15;
          OutF[(size_t)m * 1024 + n] = acc[mi][ni][r] + bias[n];
        }
      }
    }
  }
}

// ---------------- causal flash attention (swapped QK^T, dbuf glds staging) ----------------
// grid (8, B*H); block = 4 waves; block bx handles q-tiles {15-bx, bx} (17 KV-iters uniform)
// wave w owns 16 q rows. K [bh][t][64]; V^T [bh][d][t]; swapped S^T = mfma(K, Q).
__global__ __launch_bounds__(256)
void attn_fa(const unsigned short* __restrict__ Qb,
             const unsigned short* __restrict__ Kb,
             const unsigned short* __restrict__ Vtb,
             unsigned short* __restrict__ Ob) {
  __shared__ unsigned short Ks[2][64 * 64];  // [kv][k=64], chunk-swizzled
  __shared__ unsigned short Vs[2][64 * 64];  // V^T [d][kv=64], chunk-swizzled
  __shared__ unsigned short Ps[4][16 * 64];  // per-wave P [qrow][kv], chunk-swizzled
  const int tid = threadIdx.x, w = tid >> 6, lane = tid & 63;
  const int l15 = lane & 15, l4 = lane >> 4;
  const int bx = blockIdx.x, bh = blockIdx.y;
  const unsigned short* Q = Qb + ((size_t)bh << 16);
  const unsigned short* K = Kb + ((size_t)bh << 16);
  const unsigned short* Vt = Vtb + ((size_t)bh << 16);
  const int b = bh >> 4, h = bh & 15;
  const float SC = 0.125f * 1.44269504088896340736f;  // 1/sqrt(64) * log2(e)
  const float NEGINF = -__builtin_inff();

  // staging geometry: chunk C = c*256 + tid; row = C>>3; slot cc holds k-chunk cc^(row&7)
  int srow[2], skoff[2];
#pragma unroll
  for (int c = 0; c < 2; ++c) {
    int C = (c << 8) + tid;
    int row = C >> 3, cc = C & 7;
    srow[c] = row;
    skoff[c] = ((cc ^ (row & 7)) << 3);
  }
  const int sdst = (w << 6) << 3;  // wave-uniform lds element base (+c*256*8)

  for (int ph = 0; ph < 2; ++ph) {
    const int qidx = ph ? bx : (15 - bx);
    const int q0 = qidx << 6;
    const int nt = qidx + 1;
    const int qrow = q0 + (w << 4) + l15;

    short8 bq0, bq1;
    {
      const unsigned short* qp = Q + (size_t)qrow * 64 + (l4 << 3);
      bq0 = *(const short8*)qp;
      bq1 = *(const short8*)(qp + 32);
    }

    f32x4 o[4];
#pragma unroll
    for (int nf = 0; nf < 4; ++nf) o[nf] = f32x4{0.f, 0.f, 0.f, 0.f};
    float mreg = NEGINF, lreg = 0.f;

    // prologue: stage tile 0 into buf 0
#pragma unroll
    for (int c = 0; c < 2; ++c) {
      glds16(K + (size_t)(srow[c] << 6) + skoff[c], &Ks[0][(c << 11) + sdst]);
      glds16(Vt + (size_t)(srow[c] << 10) + skoff[c], &Vs[0][(c << 11) + sdst]);
    }
    __syncthreads();

    for (int it = 0; it < nt; ++it) {
      const int cur = it & 1;
      if (it + 1 < nt) {
        const int kv0n = (it + 1) << 6;
#pragma unroll
        for (int c = 0; c < 2; ++c) {
          glds16(K + (size_t)((kv0n + srow[c]) << 6) + skoff[c], &Ks[cur ^ 1][(c << 11) + sdst]);
          glds16(Vt + (size_t)(srow[c] << 10) + kv0n + skoff[c], &Vs[cur ^ 1][(c << 11) + sdst]);
        }
      }

      // S^T = K Q^T : s[n][r] = S[qrow=l15][kv = kv0 + n*16 + l4*4 + r]
      f32x4 s[4];
#pragma unroll
      for (int n = 0; n < 4; ++n) {
        const int row = (n << 4) + l15;
        const int rb = row << 6;
        short8 ak0 = *(const short8*)&Ks[cur][rb + ((l4 ^ (row & 7)) << 3)];
        short8 ak1 = *(const short8*)&Ks[cur][rb + (((4 + l4) ^ (row & 7)) << 3)];
        f32x4 a = f32x4{0.f, 0.f, 0.f, 0.f};
        a = __builtin_amdgcn_mfma_f32_16x16x32_bf16(ak0, bq0, a, 0, 0, 0);
        a = __builtin_amdgcn_mfma_f32_16x16x32_bf16(ak1, bq1, a, 0, 0, 0);
        s[n] = a;
      }

      // online softmax (exp2 domain), whole P-row slice lane-local
      const int kv0 = it << 6;
      const bool diag = (it == nt - 1);
      float p[4][4];
      float mx = NEGINF;
#pragma unroll
      for (int n = 0; n < 4; ++n)
#pragma unroll
        for (int r = 0; r < 4; ++r) {
          float v = s[n][r] * SC;
          if (diag) {
            int kvg = kv0 + (n << 4) + (l4 << 2) + r;
            v = (kvg <= qrow) ? v : NEGINF;
          }
          p[n][r] = v;
          mx = fmaxf(mx, v);
        }
      mx = fmaxf(mx, __shfl_xor(mx, 16));
      mx = fmaxf(mx, __shfl_xor(mx, 32));
      float mnew = fmaxf(mreg, mx);
      float alpha = exp2f(mreg - mnew);
      mreg = mnew;
      float rs = 0.f;
#pragma unroll
      for (int n = 0; n < 4; ++n)
#pragma unroll
        for (int r = 0; r < 4; ++r) {
          float pv = exp2f(p[n][r] - mreg);
          p[n][r] = pv;
          rs += pv;
        }
      rs += __shfl_xor(rs, 16);
      rs += __shfl_xor(rs, 32);
      lreg = lreg * alpha + rs;

      float a_r[4];
#pragma unroll
      for (int r = 0; r < 4; ++r)
        a_r[r] = __shfl(alpha, (lane & 0x30) | ((l4 << 2) | r));
#pragma unroll
      for (int nf = 0; nf < 4; ++nf)
#pragma unroll
        for (int r = 0; r < 4; ++r) o[nf][r] *= a_r[r];

      // P -> Ps (wave-local), 4x packed b64 writes
#pragma unroll
      for (int n = 0; n < 4; ++n) {
        u16x4 pk;
#pragma unroll
        for (int r = 0; r < 4; ++r) pk[r] = f2bf(p[n][r]);
        const int kc = (n << 1) + (l4 >> 1);
        char* addr = (char*)&Ps[w][0] + (l15 << 7) + ((kc ^ (l15 & 7)) << 4) + ((l4 & 1) << 3);
        *(u16x4*)addr = pk;
      }

      // O += P V  (A = P from Ps, B = V^T fragments from Vs)
      short8 pa0 = *(const short8*)((char*)&Ps[w][0] + (l15 << 7) + ((l4 ^ (l15 & 7)) << 4));
      short8 pa1 = *(const short8*)((char*)&Ps[w][0] + (l15 << 7) + (((4 + l4) ^ (l15 & 7)) << 4));
#pragma unroll
      for (int nf = 0; nf < 4; ++nf) {
        const int drow = (nf << 4) + l15;
        const int db = drow << 6;
        short8 vb0 = *(const short8*)&Vs[cur][db + ((l4 ^ (drow & 7)) << 3)];
        short8 vb1 = *(const short8*)&Vs[cur][db + (((4 + l4) ^ (drow & 7)) << 3)];
        o[nf] = __builtin_amdgcn_mfma_f32_16x16x32_bf16(pa0, vb0, o[nf], 0, 0, 0);
        o[nf] = __builtin_amdgcn_mfma_f32_16x16x32_bf16(pa1, vb1, o[nf], 0, 0, 0);
      }
      __syncthreads();
    }

    // epilogue: O rows are (l4*4+r); l lives per l15-row -> transpose via shfl
    float linv = 1.0f / lreg;
    float l_r[4];
#pragma unroll
    for (int r = 0; r < 4; ++r)
      l_r[r] = __shfl(linv, (lane & 0x30) | ((l4 << 2) | r));
#pragma unroll
    for (int r = 0; r < 4; ++r) {
      const int t = q0 + (w << 4) + (l4 << 2) + r;
      size_t base = ((size_t)(b * 1024 + t) << 10) + (h << 6);
#pragma unroll
      for (int nf = 0; nf < 4; ++nf)
        Ob[base + (nf << 4) + l15] = f2bf(o[nf][r] * l_r[r]);
    }
    __syncthreads();  // LDS quiesce before next phase's prologue staging
  }
}

// ---------------- launch ----------------

extern "C" void kernel_launch(void* const* d_in, const int* in_sizes, int n_in,
                              void* d_out, int out_size, void* d_ws, size_t ws_size,
                              hipStream_t stream) {
  const float* x  = (const float*)d_in[0];
  const float* Wq = (const float*)d_in[1];
  const float* Wk = (const float*)d_in[2];
  const float* Wv = (const float*)d_in[3];
  const float* Wo = (const float*)d_in[4];
  const float* bo = (const float*)d_in[5];
  float* out = (float*)d_out;

  unsigned char* ws = (unsigned char*)d_ws;
  unsigned short* xb  = (unsigned short*)(ws);                          // 32 MB (aliased by O later)
  unsigned short* wT  = (unsigned short*)(ws + 33554432);               // 3 x 2 MB (WqT,WkT,WvT)
  unsigned short* woT = (unsigned short*)(ws + 33554432 + 6291456);     // 2 MB
  unsigned short* qkv = (unsigned short*)(ws + 41943040);               // q,k [bh][t][d]; v^T [bh][d][t]
  unsigned short* Ob  = xb;  // x bf16 is dead after projections

  cvt_x_kernel<<<2048, 256, 0, stream>>>(x, xb, 4194304);
  cvt_w_kernel<<<4096, 256, 0, stream>>>(Wq, wT,              1 << 20, 6);
  cvt_w_kernel<<<4096, 256, 0, stream>>>(Wk, wT + (1 << 20),  1 << 20, 6);
  cvt_w_kernel<<<4096, 256, 0, stream>>>(Wv, wT + (2 << 20),  1 << 20, 6);
  cvt_w_kernel<<<4096, 256, 0, stream>>>(Wo, woT,             1 << 20, 10);

  gemm128<0><<<dim3(8, 128, 3), 256, 0, stream>>>(xb, wT, qkv, nullptr, nullptr);
  attn_fa<<<dim3(8, 256), 256, 0, stream>>>(qkv, qkv + 16777216, qkv + 33554432, Ob);
  gemm128<1><<<dim3(8, 128, 1), 256, 0, stream>>>(Ob, woT, nullptr, out, bo);
}

// Round 3
// 418.898 us; speedup vs baseline: 1.6130x; 1.0809x over previous
//
#include <hip/hip_runtime.h>
#include <stdint.h>

typedef __attribute__((ext_vector_type(8))) short short8;
typedef __attribute__((ext_vector_type(4))) float f32x4;
typedef __attribute__((ext_vector_type(4))) unsigned short u16x4;

#define DEVI static __device__ __forceinline__

DEVI unsigned short f2bf(float f) {
  unsigned int u = __builtin_bit_cast(unsigned int, f);
  u += 0x7fffu + ((u >> 16) & 1u);
  return (unsigned short)(u >> 16);
}

DEVI void glds16(const void* g, void* lds_uniform) {
  typedef const __attribute__((address_space(1))) unsigned int* gp_t;
  typedef __attribute__((address_space(3))) unsigned int* lp_t;
  __builtin_amdgcn_global_load_lds((gp_t)(uintptr_t)g, (lp_t)(uintptr_t)lds_uniform, 16, 0, 0);
}

// ---------------- conversions ----------------

__global__ __launch_bounds__(256) void cvt_x_kernel(const float* __restrict__ in,
                                                    unsigned short* __restrict__ out, int n4) {
  typedef __attribute__((ext_vector_type(4))) float f4;
  typedef __attribute__((ext_vector_type(4))) unsigned short u4;
  const f4* in4 = (const f4*)in;
  u4* out4 = (u4*)out;
  for (int i = blockIdx.x * blockDim.x + threadIdx.x; i < n4; i += gridDim.x * blockDim.x) {
    f4 v = in4[i];
    u4 o;
    o[0] = f2bf(v[0]); o[1] = f2bf(v[1]); o[2] = f2bf(v[2]); o[3] = f2bf(v[3]);
    out4[i] = o;
  }
}

// transpose-convert: in fp32 [B][R=1024][C], out bf16 [B][C][R]; C,R pow2, R=1024
__global__ __launch_bounds__(256) void cvt_w_kernel(const float* __restrict__ in,
                                                    unsigned short* __restrict__ out,
                                                    int total, int log2C) {
  int i = blockIdx.x * blockDim.x + threadIdx.x;
  if (i >= total) return;
  int r = i & 1023;
  int rest = i >> 10;
  int c = rest & ((1 << log2C) - 1);
  int b = rest >> log2C;
  out[i] = f2bf(in[((((size_t)b << 10) | (size_t)r) << log2C) | (size_t)c]);
}

// ---------------- GEMM: C[M x N] = A[M x K] * Bt[N x K]^T, K=1024, M=16384 ----------------
// MODE 0: N=3072 fused QKV; n<2048 -> bf16 scatter [bh][t][d]; n>=2048 -> V^T [bh][d][t] pack x4
// MODE 1: N=1024, out fp32 row-major [M][1024] + bias
// 1-D grid, XCD-bijective swizzle + 4x4 supertiles (sn-fastest within XCD => exclusive A-stripes)
template <int MODE>
__global__ __launch_bounds__(256)
void gemm128(const unsigned short* __restrict__ A,
             const unsigned short* __restrict__ Bt,
             unsigned short* __restrict__ OutB,
             float* __restrict__ OutF,
             const float* __restrict__ bias) {
  __shared__ unsigned short As[128 * 64];  // [row][64], chunk-swizzled
  __shared__ unsigned short Bs[128 * 64];
  const int tid = threadIdx.x;
  const int w = tid >> 6, lane = tid & 63;
  const int l15 = lane & 15, l4 = lane >> 4;

  // grid decode: nwg = 3072 (MODE0) or 1024 (MODE1); SN = n-supertiles (6 or 2)
  const int SN = (MODE == 0) ? 6 : 2;
  const int q8 = (MODE == 0) ? 384 : 128;
  const int phys = blockIdx.x;
  const int wgid = (phys & 7) * q8 + (phys >> 3);
  const int st = wgid >> 4, loc = wgid & 15;
  const int sm = st / SN, sn = st % SN;
  const int bm = (((sm << 2) + (loc >> 2)) << 7);
  const int bn = (((sn << 2) + (loc & 3)) << 7);

  f32x4 acc[4][4];
#pragma unroll
  for (int i = 0; i < 4; ++i)
#pragma unroll
    for (int j = 0; j < 4; ++j) acc[i][j] = f32x4{0.f, 0.f, 0.f, 0.f};

  const int wr = w >> 1, wc = w & 1;

  int Crow[4], Kel[4];
#pragma unroll
  for (int j = 0; j < 4; ++j) {
    int C = (((j << 2) + w) << 6) + lane;
    int row = C >> 3, cc = C & 7;
    Crow[j] = row;
    Kel[j] = ((cc ^ (row & 7)) << 3);
  }

  for (int kt = 0; kt < 16; ++kt) {
    int k0 = kt << 6;
#pragma unroll
    for (int j = 0; j < 4; ++j) {
      const unsigned short* g = A + (size_t)(bm + Crow[j]) * 1024 + k0 + Kel[j];
      glds16(g, &As[(size_t)(((j << 2) + w) << 6) * 8]);
    }
#pragma unroll
    for (int j = 0; j < 4; ++j) {
      const unsigned short* g = Bt + (size_t)(bn + Crow[j]) * 1024 + k0 + Kel[j];
      glds16(g, &Bs[(size_t)(((j << 2) + w) << 6) * 8]);
    }
    __syncthreads();
    __builtin_amdgcn_s_setprio(1);
#pragma unroll
    for (int ks = 0; ks < 2; ++ks) {
      short8 af[4], bfr[4];
#pragma unroll
      for (int mi = 0; mi < 4; ++mi) {
        int row = (wr << 6) + (mi << 4) + l15;
        int ch = ((ks << 2) + l4) ^ (row & 7);
        af[mi] = *(const short8*)&As[(row << 6) + (ch << 3)];
      }
#pragma unroll
      for (int ni = 0; ni < 4; ++ni) {
        int row = (wc << 6) + (ni << 4) + l15;
        int ch = ((ks << 2) + l4) ^ (row & 7);
        bfr[ni] = *(const short8*)&Bs[(row << 6) + (ch << 3)];
      }
#pragma unroll
      for (int mi = 0; mi < 4; ++mi)
#pragma unroll
        for (int ni = 0; ni < 4; ++ni)
          acc[mi][ni] = __builtin_amdgcn_mfma_f32_16x16x32_bf16(af[mi], bfr[ni], acc[mi][ni], 0, 0, 0);
    }
    __builtin_amdgcn_s_setprio(0);
    __syncthreads();
  }

  if (MODE == 0) {
    const int nb = bn + (wc << 6);
    const int z = nb >> 10;  // block-uniform (bn step 128, wc*64 < 128)
    if (z < 2) {
      unsigned short* Oz = OutB + (size_t)z * 16777216;
#pragma unroll
      for (int mi = 0; mi < 4; ++mi) {
#pragma unroll
        for (int r = 0; r < 4; ++r) {
          int m = bm + (wr << 6) + (mi << 4) + (l4 << 2) + r;
          int b = m >> 10, t = m & 1023;
#pragma unroll
          for (int ni = 0; ni < 4; ++ni) {
            int n1 = (nb + (ni << 4) + l15) & 1023;
            int h = n1 >> 6, d = n1 & 63;
            Oz[((size_t)(b * 16 + h) * 1024 + t) * 64 + d] = f2bf(acc[mi][ni][r]);
          }
        }
      }
    } else {
      // V^T: [bh][d][t], pack 4 consecutive t per lane
      unsigned short* Oz = OutB + (size_t)2 * 16777216;
#pragma unroll
      for (int mi = 0; mi < 4; ++mi) {
        int tb = bm + (wr << 6) + (mi << 4) + (l4 << 2);
        int bb = tb >> 10, tt = tb & 1023;
#pragma unroll
        for (int ni = 0; ni < 4; ++ni) {
          int n1 = (nb + (ni << 4) + l15) & 1023;
          int hh = n1 >> 6, dd = n1 & 63;
          u16x4 pk;
#pragma unroll
          for (int r = 0; r < 4; ++r) pk[r] = f2bf(acc[mi][ni][r]);
          *(u16x4*)&Oz[(((size_t)((bb << 4) + hh) << 6) + (size_t)dd) * 1024 + tt] = pk;
        }
      }
    }
  } else {
#pragma unroll
    for (int mi = 0; mi < 4; ++mi) {
#pragma unroll
      for (int r = 0; r < 4; ++r) {
        int m = bm + (wr << 6) + (mi << 4) + (l4 << 2) + r;
#pragma unroll
        for (int ni = 0; ni < 4; ++ni) {
          int n = bn + (wc << 6) + (ni << 4) + l15;
          OutF[(size_t)m * 1024 + n] = acc[mi][ni][r] + bias[n];
        }
      }
    }
  }
}

// ---------------- causal flash attention (swapped QK^T, single-barrier dbuf) ----------------
// 1-D grid 2048, XCD swizzle: each XCD owns 32 consecutive bh (K/V L2-resident per XCD).
// block bx handles q-tiles {15-bx, bx} (17 KV-iters uniform). wave w owns 16 q rows.
// K [bh][t][64]; V^T [bh][d][t]; swapped S^T = mfma(K, Q) so softmax is lane-local.
__global__ __launch_bounds__(256)
void attn_fa(const unsigned short* __restrict__ Qb,
             const unsigned short* __restrict__ Kb,
             const unsigned short* __restrict__ Vtb,
             unsigned short* __restrict__ Ob) {
  __shared__ unsigned short Ks[2][64 * 64];  // [kv][k=64], chunk-swizzled
  __shared__ unsigned short Vs[2][64 * 64];  // V^T [d][kv=64], chunk-swizzled
  __shared__ unsigned short Ps[4][16 * 64];  // per-wave P [qrow][kv], chunk-swizzled
  const int tid = threadIdx.x, w = tid >> 6, lane = tid & 63;
  const int l15 = lane & 15, l4 = lane >> 4;
  const int phys = blockIdx.x;
  const int ord = phys >> 3;
  const int bx = ord & 7;
  const int bh = ((phys & 7) << 5) | (ord >> 3);
  const unsigned short* Q = Qb + ((size_t)bh << 16);
  const unsigned short* K = Kb + ((size_t)bh << 16);
  const unsigned short* Vt = Vtb + ((size_t)bh << 16);
  const int b = bh >> 4, h = bh & 15;
  const float SC = 0.125f * 1.44269504088896340736f;  // 1/sqrt(64) * log2(e)
  const float NEGINF = -__builtin_inff();

  // staging geometry: chunk C = c*256 + tid; row = C>>3; slot cc holds k-chunk cc^(row&7)
  int srow[2], skoff[2];
#pragma unroll
  for (int c = 0; c < 2; ++c) {
    int C = (c << 8) + tid;
    int row = C >> 3, cc = C & 7;
    srow[c] = row;
    skoff[c] = ((cc ^ (row & 7)) << 3);
  }
  const int sdst = (w << 6) << 3;  // wave-uniform lds element base (+c*256*8)

  for (int ph = 0; ph < 2; ++ph) {
    const int qidx = ph ? bx : (15 - bx);
    const int q0 = qidx << 6;
    const int nt = qidx + 1;
    const int qrow = q0 + (w << 4) + l15;

    short8 bq0, bq1;
    {
      const unsigned short* qp = Q + (size_t)qrow * 64 + (l4 << 3);
      bq0 = *(const short8*)qp;
      bq1 = *(const short8*)(qp + 32);
    }

    f32x4 o[4];
#pragma unroll
    for (int nf = 0; nf < 4; ++nf) o[nf] = f32x4{0.f, 0.f, 0.f, 0.f};
    float mreg = NEGINF, lreg = 0.f;

    // prologue: stage tile 0 into buf 0 (last iteration's barrier guarantees LDS quiesce)
#pragma unroll
    for (int c = 0; c < 2; ++c) {
      glds16(K + (size_t)(srow[c] << 6) + skoff[c], &Ks[0][(c << 11) + sdst]);
      glds16(Vt + (size_t)(srow[c] << 10) + skoff[c], &Vs[0][(c << 11) + sdst]);
    }
    __syncthreads();

    for (int it = 0; it < nt; ++it) {
      const int cur = it & 1;
      // issue next-tile stage into buf^1 (nobody reads buf^1 this iteration)
      if (it + 1 < nt) {
        const int kv0n = (it + 1) << 6;
#pragma unroll
        for (int c = 0; c < 2; ++c) {
          glds16(K + (size_t)((kv0n + srow[c]) << 6) + skoff[c], &Ks[cur ^ 1][(c << 11) + sdst]);
          glds16(Vt + (size_t)(srow[c] << 10) + kv0n + skoff[c], &Vs[cur ^ 1][(c << 11) + sdst]);
        }
      }

      // S^T = K Q^T : s[n][r] = S[qrow=l15][kv = kv0 + n*16 + l4*4 + r]
      f32x4 s[4];
      __builtin_amdgcn_s_setprio(1);
#pragma unroll
      for (int n = 0; n < 4; ++n) {
        const int row = (n << 4) + l15;
        const int rb = row << 6;
        short8 ak0 = *(const short8*)&Ks[cur][rb + ((l4 ^ (row & 7)) << 3)];
        short8 ak1 = *(const short8*)&Ks[cur][rb + (((4 + l4) ^ (row & 7)) << 3)];
        f32x4 a = f32x4{0.f, 0.f, 0.f, 0.f};
        a = __builtin_amdgcn_mfma_f32_16x16x32_bf16(ak0, bq0, a, 0, 0, 0);
        a = __builtin_amdgcn_mfma_f32_16x16x32_bf16(ak1, bq1, a, 0, 0, 0);
        s[n] = a;
      }
      __builtin_amdgcn_s_setprio(0);

      // online softmax (exp2 domain), whole P-row slice lane-local
      const int kv0 = it << 6;
      const bool diag = (it == nt - 1);
      float p[4][4];
      float mx = NEGINF;
#pragma unroll
      for (int n = 0; n < 4; ++n)
#pragma unroll
        for (int r = 0; r < 4; ++r) {
          float v = s[n][r] * SC;
          if (diag) {
            int kvg = kv0 + (n << 4) + (l4 << 2) + r;
            v = (kvg <= qrow) ? v : NEGINF;
          }
          p[n][r] = v;
          mx = fmaxf(mx, v);
        }
      mx = fmaxf(mx, __shfl_xor(mx, 16));
      mx = fmaxf(mx, __shfl_xor(mx, 32));
      float mnew = fmaxf(mreg, mx);
      float alpha = exp2f(mreg - mnew);
      mreg = mnew;
      float rs = 0.f;
#pragma unroll
      for (int n = 0; n < 4; ++n)
#pragma unroll
        for (int r = 0; r < 4; ++r) {
          float pv = exp2f(p[n][r] - mreg);
          p[n][r] = pv;
          rs += pv;
        }
      rs += __shfl_xor(rs, 16);
      rs += __shfl_xor(rs, 32);
      lreg = lreg * alpha + rs;

      float a_r[4];
#pragma unroll
      for (int r = 0; r < 4; ++r)
        a_r[r] = __shfl(alpha, (lane & 0x30) | ((l4 << 2) | r));
#pragma unroll
      for (int nf = 0; nf < 4; ++nf)
#pragma unroll
        for (int r = 0; r < 4; ++r) o[nf][r] *= a_r[r];

      // P -> Ps (wave-local region; same-wave DS ops are in-order => no barrier)
#pragma unroll
      for (int n = 0; n < 4; ++n) {
        u16x4 pk;
#pragma unroll
        for (int r = 0; r < 4; ++r) pk[r] = f2bf(p[n][r]);
        const int kc = (n << 1) + (l4 >> 1);
        char* addr = (char*)&Ps[w][0] + (l15 << 7) + ((kc ^ (l15 & 7)) << 4) + ((l4 & 1) << 3);
        *(u16x4*)addr = pk;
      }

      // O += P V  (A = P from Ps, B = V^T fragments from Vs)
      short8 pa0 = *(const short8*)((char*)&Ps[w][0] + (l15 << 7) + ((l4 ^ (l15 & 7)) << 4));
      short8 pa1 = *(const short8*)((char*)&Ps[w][0] + (l15 << 7) + (((4 + l4) ^ (l15 & 7)) << 4));
      __builtin_amdgcn_s_setprio(1);
#pragma unroll
      for (int nf = 0; nf < 4; ++nf) {
        const int drow = (nf << 4) + l15;
        const int db = drow << 6;
        short8 vb0 = *(const short8*)&Vs[cur][db + ((l4 ^ (drow & 7)) << 3)];
        short8 vb1 = *(const short8*)&Vs[cur][db + (((4 + l4) ^ (drow & 7)) << 3)];
        o[nf] = __builtin_amdgcn_mfma_f32_16x16x32_bf16(pa0, vb0, o[nf], 0, 0, 0);
        o[nf] = __builtin_amdgcn_mfma_f32_16x16x32_bf16(pa1, vb1, o[nf], 0, 0, 0);
      }
      __builtin_amdgcn_s_setprio(0);
      // single barrier: drains this wave's glds (vmcnt) + orders buf^1 for next iter
      __syncthreads();
    }

    // epilogue (registers only): O rows are (l4*4+r); l lives per l15-row -> shfl transpose
    float linv = 1.0f / lreg;
    float l_r[4];
#pragma unroll
    for (int r = 0; r < 4; ++r)
      l_r[r] = __shfl(linv, (lane & 0x30) | ((l4 << 2) | r));
#pragma unroll
    for (int r = 0; r < 4; ++r) {
      const int t = q0 + (w << 4) + (l4 << 2) + r;
      size_t base = ((size_t)(b * 1024 + t) << 10) + (h << 6);
#pragma unroll
      for (int nf = 0; nf < 4; ++nf)
        Ob[base + (nf << 4) + l15] = f2bf(o[nf][r] * l_r[r]);
    }
  }
}

// ---------------- launch ----------------

extern "C" void kernel_launch(void* const* d_in, const int* in_sizes, int n_in,
                              void* d_out, int out_size, void* d_ws, size_t ws_size,
                              hipStream_t stream) {
  const float* x  = (const float*)d_in[0];
  const float* Wq = (const float*)d_in[1];
  const float* Wk = (const float*)d_in[2];
  const float* Wv = (const float*)d_in[3];
  const float* Wo = (const float*)d_in[4];
  const float* bo = (const float*)d_in[5];
  float* out = (float*)d_out;

  unsigned char* ws = (unsigned char*)d_ws;
  unsigned short* xb  = (unsigned short*)(ws);                          // 32 MB (aliased by O later)
  unsigned short* wT  = (unsigned short*)(ws + 33554432);               // 3 x 2 MB (WqT,WkT,WvT contiguous)
  unsigned short* woT = (unsigned short*)(ws + 33554432 + 6291456);     // 2 MB
  unsigned short* qkv = (unsigned short*)(ws + 41943040);               // q,k [bh][t][d]; v^T [bh][d][t]
  unsigned short* Ob  = xb;  // x bf16 is dead after projections

  cvt_x_kernel<<<2048, 256, 0, stream>>>(x, xb, 4194304);
  cvt_w_kernel<<<4096, 256, 0, stream>>>(Wq, wT,              1 << 20, 6);
  cvt_w_kernel<<<4096, 256, 0, stream>>>(Wk, wT + (1 << 20),  1 << 20, 6);
  cvt_w_kernel<<<4096, 256, 0, stream>>>(Wv, wT + (2 << 20),  1 << 20, 6);
  cvt_w_kernel<<<4096, 256, 0, stream>>>(Wo, woT,             1 << 20, 10);

  gemm128<0><<<3072, 256, 0, stream>>>(xb, wT, qkv, nullptr, nullptr);
  attn_fa<<<2048, 256, 0, stream>>>(qkv, qkv + 16777216, qkv + 33554432, Ob);
  gemm128<1><<<1024, 256, 0, stream>>>(Ob, woT, nullptr, out, bo);
}